// Round 1
// baseline (119.005 us; speedup 1.0000x reference)
//
#include <hip/hip_runtime.h>
#include <math.h>

// Dims (fixed by the problem)
#define NB     16
#define NCIN   384
#define NH     64
#define NW     64
#define NHEADS 4
#define NHD    24
#define NDIM   96            // HEADS*HD
#define NSTR   5
#define NDT    480           // NSTR*NDIM
#define NAG    64            // 8x8 agents
#define NBH    64            // NB*NHEADS

// ---------------------------------------------------------------------------
// Kernel 1: 8x8 average pool of x: (16,384,64,64) -> x8 (16*384, 64)
// one wave per (b,c) plane, lane = output pixel
// ---------------------------------------------------------------------------
__global__ void __launch_bounds__(256) k_pool(const float* __restrict__ x,
                                              float* __restrict__ x8) {
    int plane = blockIdx.x * 4 + (threadIdx.x >> 6);   // b*384 + c
    int lane  = threadIdx.x & 63;
    int py = lane >> 3, px = lane & 7;
    const float* base = x + (size_t)plane * 4096 + py * 8 * 64 + px * 8;
    float acc = 0.f;
#pragma unroll
    for (int rr = 0; rr < 8; ++rr) {
        float4 a = *reinterpret_cast<const float4*>(base + rr * 64);
        float4 b = *reinterpret_cast<const float4*>(base + rr * 64 + 4);
        acc += a.x + a.y + a.z + a.w + b.x + b.y + b.z + b.w;
    }
    x8[plane * 64 + lane] = acc * (1.f / 64.f);
}

// ---------------------------------------------------------------------------
// Kernel 2: y8[row=b*64+pix][d] = sum_c x8[b][c][pix]*W1[c][d] + b1[d]
// M=1024 (per-b 64 rows), N=480 (padded to 512), K=384
// grid (8 d-tiles, 16 b), 512 threads, tile 64x64, K-chunks of 64
// ---------------------------------------------------------------------------
#define KC 64
__global__ void __launch_bounds__(512) k_proj(const float* __restrict__ x8,
                                              const float* __restrict__ W1,
                                              const float* __restrict__ b1,
                                              float* __restrict__ y8) {
    __shared__ float AL[KC][64];   // [c][pix]
    __shared__ float BL[KC][64];   // [c][d]
    const int b  = blockIdx.y;
    const int d0 = blockIdx.x * 64;
    const int tid = threadIdx.x;
    const int px0 = (tid & 15) * 4;
    const int dg  = tid >> 4;           // 0..31
    float acc[4][2] = {};
    for (int c0 = 0; c0 < 384; c0 += KC) {
        __syncthreads();
#pragma unroll
        for (int i = 0; i < 8; ++i) {
            int idx = tid + i * 512;     // 0..4095
            int c = idx >> 6, j = idx & 63;
            AL[c][j] = x8[(b * 384 + c0 + c) * 64 + j];
            int d = d0 + j;
            BL[c][j] = (d < NDT) ? W1[(c0 + c) * NDT + d] : 0.f;
        }
        __syncthreads();
#pragma unroll 8
        for (int c = 0; c < KC; ++c) {
            float4 a = *reinterpret_cast<const float4*>(&AL[c][px0]);
            float2 w = *reinterpret_cast<const float2*>(&BL[c][dg * 2]);
            acc[0][0] += a.x * w.x; acc[0][1] += a.x * w.y;
            acc[1][0] += a.y * w.x; acc[1][1] += a.y * w.y;
            acc[2][0] += a.z * w.x; acc[2][1] += a.z * w.y;
            acc[3][0] += a.w * w.x; acc[3][1] += a.w * w.y;
        }
    }
#pragma unroll
    for (int p = 0; p < 4; ++p) {
        int pix = px0 + p;
#pragma unroll
        for (int q = 0; q < 2; ++q) {
            int d = d0 + dg * 2 + q;
            if (d < NDT)
                y8[(b * 64 + pix) * NDT + d] = acc[p][q] + b1[d];
        }
    }
}

// ---------------------------------------------------------------------------
// Kernel 3: per (B, head): clustering (hard + soft), cosine attention,
// out8[B][h*24+c][n].  grid 64 blocks (B*4+h), 256 threads (4 waves).
// ---------------------------------------------------------------------------
__global__ void __launch_bounds__(256) k_cluster(const float* __restrict__ y8,
                                                 const float* __restrict__ salpha,
                                                 const float* __restrict__ sbeta,
                                                 float* __restrict__ out8) {
    __shared__ float sl[5][64][25];     // [stream][pix][c] pitch 25 (bank spread)
    __shared__ float y2s[5][4][24];     // 2x2-pooled cluster centers per stream
    __shared__ float wb[2][64][5];      // assignment weights [module][token][m]
    __shared__ float aggL[8][25];       // agg sums; col 24 = count
    __shared__ float anL[8][24];        // normalized agg
    __shared__ float normL[8];

    const int bp = blockIdx.x;          // 0..63
    const int Bi = bp >> 2, h = bp & 3;
    const int tid = threadIdx.x;
    const int lane = tid & 63, wid = tid >> 6;

    // stage the 5 stream slices for this (B, head): 5*64*24 floats
    for (int idx = tid; idx < 5 * 64 * 24; idx += 256) {
        int c = idx % 24;
        int pix = (idx / 24) & 63;
        int s = idx / (24 * 64);
        sl[s][pix][c] = y8[(Bi * 64 + pix) * NDT + s * NDIM + h * NHD + c];
    }
    __syncthreads();
    // 2x2 cluster-center pooling (exact pool of the 8x8 grid quadrants)
    for (int idx = tid; idx < 5 * 4 * 24; idx += 256) {
        int c = idx % 24;
        int m = (idx / 24) & 3;
        int s = idx / 96;
        int my = m >> 1, mx = m & 1;
        float acc = 0.f;
        for (int ry = 0; ry < 4; ++ry)
            for (int rx = 0; rx < 4; ++rx)
                acc += sl[s][(my * 4 + ry) * 8 + mx * 4 + rx][c];
        y2s[s][m][c] = acc * (1.f / 16.f);
    }
    __syncthreads();
    // per-module assignment weights: wave 0 -> module 0 (hard), wave 1 -> module 1 (soft)
    if (wid < 2) {
        const int i = wid, ks = 1 + 2 * i;
        float ka[24];
        float sumk2 = 0.f;
#pragma unroll
        for (int c = 0; c < 24; ++c) { ka[c] = sl[ks][lane][c]; sumk2 += ka[c] * ka[c]; }
        float sim[4];
#pragma unroll
        for (int m = 0; m < 4; ++m) {
            float kc2 = 0.f, dt = 0.f;
#pragma unroll
            for (int c = 0; c < 24; ++c) {
                float kv = y2s[ks][m][c];
                kc2 += kv * kv; dt += kv * ka[c];
            }
            sim[m] = 2.f * dt - kc2 - sumk2;    // = -d2
        }
        float w[4];
        if (i == 0) {
            int am = 0; float bv = sim[0];
#pragma unroll
            for (int m = 1; m < 4; ++m) if (sim[m] > bv) { bv = sim[m]; am = m; }
#pragma unroll
            for (int m = 0; m < 4; ++m) w[m] = (m == am) ? 1.f : 0.f;
        } else {
            float mx = fmaxf(fmaxf(sim[0], sim[1]), fmaxf(sim[2], sim[3]));
            float sum = 0.f;
#pragma unroll
            for (int m = 0; m < 4; ++m) { w[m] = expf(sim[m] - mx); sum += w[m]; }
            float inv = 1.f / sum;
#pragma unroll
            for (int m = 0; m < 4; ++m) w[m] *= inv;
        }
#pragma unroll
        for (int m = 0; m < 4; ++m) wb[i][lane][m] = w[m];
    }
    __syncthreads();
    // aggregate: raw sums sum_n w[m][n]*v[n][c] (c==24 -> count)
    if (tid < 200) {
        int i = tid / 100, rem = tid % 100;
        int m = rem / 25, c = rem % 25;
        int vs = 2 + 2 * i;
        float s = 0.f;
        for (int n = 0; n < 64; ++n) {
            float wv = wb[i][n][m];
            s += (c < 24) ? wv * sl[vs][n][c] : wv;
        }
        aggL[i * 4 + m][c] = s;
    }
    __syncthreads();
    // finalize agg = (vc + sum) / (1 + count)
    if (tid < 192) {
        int mm = tid / 24, c = tid % 24;
        int i = mm >> 2, m = mm & 3;
        aggL[mm][c] = (y2s[2 + 2 * i][m][c] + aggL[mm][c]) / (1.f + aggL[mm][24]);
    }
    __syncthreads();
    if (tid < 8) {
        float s = 0.f;
        for (int c = 0; c < 24; ++c) s += aggL[tid][c] * aggL[tid][c];
        normL[tid] = sqrtf(s) + 1e-6f;
    }
    __syncthreads();
    if (tid < 192) {
        int mm = tid / 24, c = tid % 24;
        anL[mm][c] = aggL[mm][c] / normL[mm];
    }
    __syncthreads();
    // per-token cosine-sim softmax + output; waves compute redundantly,
    // each wave stores a 6-channel slice of the 24 output channels.
    {
        const int n = lane;
        float pa[24]; float p2 = 0.f;
#pragma unroll
        for (int c = 0; c < 24; ++c) { pa[c] = sl[0][n][c]; p2 += pa[c] * pa[c]; }
        float pinv = 1.f / (sqrtf(p2) + 1e-6f);
        float s2[8];
#pragma unroll
        for (int mm = 0; mm < 8; ++mm) {
            float dt = 0.f;
#pragma unroll
            for (int c = 0; c < 24; ++c) dt += anL[mm][c] * pa[c];
            s2[mm] = salpha[mm] * (dt * pinv) + sbeta[mm];
        }
        float mx = s2[0];
#pragma unroll
        for (int mm = 1; mm < 8; ++mm) mx = fmaxf(mx, s2[mm]);
        float sum = 0.f;
#pragma unroll
        for (int mm = 0; mm < 8; ++mm) { s2[mm] = expf(s2[mm] - mx); sum += s2[mm]; }
        float inv = 1.f / sum;
        const int c0 = wid * 6;
#pragma unroll
        for (int cc = 0; cc < 6; ++cc) {
            int c = c0 + cc;
            float v = 0.f;
#pragma unroll
            for (int mm = 0; mm < 8; ++mm) v += aggL[mm][c] * (s2[mm] * inv);
            out8[(Bi * NDIM + h * NHD + c) * 64 + n] = v;
        }
    }
}

// ---------------------------------------------------------------------------
// Kernel 4: z8[B][o][n] = sum_d out8[B][d][n] * W2[d][o]   (K=96)
// grid (6 o-tiles of 64, 16 B), 256 threads, 4x4 register tile
// ---------------------------------------------------------------------------
__global__ void __launch_bounds__(256) k_proj2(const float* __restrict__ out8,
                                               const float* __restrict__ W2,
                                               float* __restrict__ z8) {
    __shared__ float AL[96][64];   // [d][n]
    __shared__ float WL[96][64];   // [d][o_local]
    const int Bi = blockIdx.y, o0 = blockIdx.x * 64;
    const int tid = threadIdx.x;
    for (int idx = tid; idx < 96 * 64; idx += 256) {
        int d = idx >> 6, j = idx & 63;
        AL[d][j] = out8[(Bi * NDIM + d) * 64 + j];
        WL[d][j] = W2[d * NCIN + o0 + j];
    }
    __syncthreads();
    const int n4 = (tid & 15) * 4, o4 = (tid >> 4) * 4;
    float acc[4][4] = {};
#pragma unroll 4
    for (int d = 0; d < 96; ++d) {
        float4 a = *reinterpret_cast<const float4*>(&AL[d][n4]);
        float4 w = *reinterpret_cast<const float4*>(&WL[d][o4]);
        acc[0][0] += w.x * a.x; acc[0][1] += w.x * a.y; acc[0][2] += w.x * a.z; acc[0][3] += w.x * a.w;
        acc[1][0] += w.y * a.x; acc[1][1] += w.y * a.y; acc[1][2] += w.y * a.z; acc[1][3] += w.y * a.w;
        acc[2][0] += w.z * a.x; acc[2][1] += w.z * a.y; acc[2][2] += w.z * a.z; acc[2][3] += w.z * a.w;
        acc[3][0] += w.w * a.x; acc[3][1] += w.w * a.y; acc[3][2] += w.w * a.z; acc[3][3] += w.w * a.w;
    }
#pragma unroll
    for (int oi = 0; oi < 4; ++oi) {
        float4 v = make_float4(acc[oi][0], acc[oi][1], acc[oi][2], acc[oi][3]);
        *reinterpret_cast<float4*>(&z8[(size_t)(Bi * NCIN + o0 + o4 + oi) * 64 + n4]) = v;
    }
}

// ---------------------------------------------------------------------------
// Kernel 5: bilinear 8->64 upsample + bias (jax half-pixel, clamped edges)
// grid (96 o-groups of 4, 16 B), 256 threads; thread = one output row (o,y)
// ---------------------------------------------------------------------------
__global__ void __launch_bounds__(256) k_up(const float* __restrict__ z8,
                                            const float* __restrict__ b2,
                                            float* __restrict__ out) {
    __shared__ float zt[4][72];    // [o_local][iy*9+ix]  (9-pitch: bank spread)
    const int Bi = blockIdx.y;
    const int o0 = blockIdx.x * 4;
    const int tid = threadIdx.x;
    {
        int ol = tid >> 6, n = tid & 63;
        zt[ol][(n >> 3) * 9 + (n & 7)] = z8[(size_t)(Bi * NCIN + o0 + ol) * 64 + n];
    }
    __syncthreads();
    const int ol = tid >> 6, y = tid & 63;
    float u  = 0.125f * (float)y - 0.4375f;
    float uc = fminf(fmaxf(u, 0.f), 7.f);
    int iy0 = (int)uc;
    int iy1 = iy0 + 1 > 7 ? 7 : iy0 + 1;
    float fy = uc - (float)iy0;
    float bias = b2[o0 + ol];

    float r0[8], r1[8], ry[8];
#pragma unroll
    for (int ix = 0; ix < 8; ++ix) {
        r0[ix] = zt[ol][iy0 * 9 + ix];
        r1[ix] = zt[ol][iy1 * 9 + ix];
    }
#pragma unroll
    for (int ix = 0; ix < 8; ++ix)
        ry[ix] = r0[ix] + fy * (r1[ix] - r0[ix]) + bias;

    float* orow = out + ((size_t)(Bi * NCIN + o0 + ol) * 64 + y) * 64;
#pragma unroll
    for (int xq = 0; xq < 16; ++xq) {
        float vv[4];
#pragma unroll
        for (int j = 0; j < 4; ++j) {
            const int xx = xq * 4 + j;
            const float ux  = 0.125f * (float)xx - 0.4375f;
            const float uxc = fminf(fmaxf(ux, 0.f), 7.f);
            const int ix0 = (int)uxc;               // compile-time after unroll
            const int ix1 = ix0 + 1 > 7 ? 7 : ix0 + 1;
            const float fx = uxc - (float)ix0;
            vv[j] = ry[ix0] + fx * (ry[ix1] - ry[ix0]);
        }
        *reinterpret_cast<float4*>(orow + xq * 4) = make_float4(vv[0], vv[1], vv[2], vv[3]);
    }
}

// ---------------------------------------------------------------------------
extern "C" void kernel_launch(void* const* d_in, const int* in_sizes, int n_in,
                              void* d_out, int out_size, void* d_ws, size_t ws_size,
                              hipStream_t stream) {
    const float* x  = (const float*)d_in[0];
    const float* W1 = (const float*)d_in[1];
    const float* b1 = (const float*)d_in[2];
    const float* W2 = (const float*)d_in[3];
    const float* b2 = (const float*)d_in[4];
    const float* sa = (const float*)d_in[5];
    const float* sb = (const float*)d_in[6];
    float* out = (float*)d_out;

    float* x8 = (float*)d_ws;                 // 16*384*64      = 393216 f
    float* y8 = x8 + 16 * 384 * 64;           // 1024*480       = 491520 f
    float* o8 = y8 + 1024 * 480;              // 16*96*64       =  98304 f
    float* z8 = o8 + 16 * 96 * 64;            // 16*384*64      = 393216 f
                                              // total ~5.3 MB of ws

    k_pool<<<dim3(16 * 384 / 4), dim3(256), 0, stream>>>(x, x8);
    k_proj<<<dim3(8, 16), dim3(512), 0, stream>>>(x8, W1, b1, y8);
    k_cluster<<<dim3(64), dim3(256), 0, stream>>>(y8, sa, sb, o8);
    k_proj2<<<dim3(6, 16), dim3(256), 0, stream>>>(o8, W2, z8);
    k_up<<<dim3(96, 16), dim3(256), 0, stream>>>(z8, b2, out);
}

// Round 2
// 67.338 us; speedup vs baseline: 1.7673x; 1.7673x over previous
//
#include <hip/hip_runtime.h>
#include <math.h>

// Dims (fixed by the problem)
#define NB     16
#define NCIN   384
#define NHD    24
#define NDIM   96            // HEADS*HD
#define NSTR   5
#define NDT    480           // NSTR*NDIM

// ---------------------------------------------------------------------------
// Kernel 1: 8x8 average pool of x: (16,384,64,64) -> x8 (16*384, 64)
// one wave per (b,c) plane, lane = output pixel
// ---------------------------------------------------------------------------
__global__ void __launch_bounds__(256) k_pool(const float* __restrict__ x,
                                              float* __restrict__ x8) {
    int plane = blockIdx.x * 4 + (threadIdx.x >> 6);   // b*384 + c
    int lane  = threadIdx.x & 63;
    int py = lane >> 3, px = lane & 7;
    const float* base = x + (size_t)plane * 4096 + py * 8 * 64 + px * 8;
    float acc = 0.f;
#pragma unroll
    for (int rr = 0; rr < 8; ++rr) {
        float4 a = *reinterpret_cast<const float4*>(base + rr * 64);
        float4 b = *reinterpret_cast<const float4*>(base + rr * 64 + 4);
        acc += a.x + a.y + a.z + a.w + b.x + b.y + b.z + b.w;
    }
    x8[plane * 64 + lane] = acc * (1.f / 64.f);
}

// ---------------------------------------------------------------------------
// Kernel 2: y8[row=b*64+pix][d] = sum_c x8[b][c][pix]*W1[c][d] + b1[d]
// grid (8 d-tiles, 32 pix-tiles) = 256 blocks, 256 threads.
// tile: 32 pix x 64 d, thread = 2 pix x 4 d (8 outs).
// per-CU per-k: LDS 6KB (48cy) < VALU 64cy -> VALU-bound (~2.6us roofline)
// ---------------------------------------------------------------------------
#define KC 64
__global__ void __launch_bounds__(256) k_proj(const float* __restrict__ x8,
                                              const float* __restrict__ W1,
                                              const float* __restrict__ b1,
                                              float* __restrict__ y8) {
    __shared__ float AL[KC][32];   // [c][pix]  8 KB
    __shared__ float BL[KC][64];   // [c][d]   16 KB
    const int b    = blockIdx.y >> 1;
    const int pix0 = (blockIdx.y & 1) * 32;
    const int d0   = blockIdx.x * 64;
    const int tid  = threadIdx.x;
    const int pxg  = (tid & 15) * 2;     // pix pair
    const int dg   = (tid >> 4) * 4;     // 4 d's
    float acc[2][4] = {};
    for (int c0 = 0; c0 < 384; c0 += KC) {
        __syncthreads();
#pragma unroll
        for (int i = 0; i < 2; ++i) {    // AL: 512 float4
            int f = tid + i * 256;
            int c = f >> 3, pg = f & 7;
            *reinterpret_cast<float4*>(&AL[c][pg * 4]) =
                *reinterpret_cast<const float4*>(&x8[(b * 384 + c0 + c) * 64 + pix0 + pg * 4]);
        }
#pragma unroll
        for (int i = 0; i < 4; ++i) {    // BL: 1024 float4
            int f = tid + i * 256;
            int c = f >> 4, jg = f & 15;
            int d = d0 + jg * 4;
            float4 v = make_float4(0.f, 0.f, 0.f, 0.f);
            if (d < NDT) v = *reinterpret_cast<const float4*>(&W1[(c0 + c) * NDT + d]);
            *reinterpret_cast<float4*>(&BL[c][jg * 4]) = v;
        }
        __syncthreads();
#pragma unroll 8
        for (int c = 0; c < KC; ++c) {
            float2 a = *reinterpret_cast<const float2*>(&AL[c][pxg]);
            float4 w = *reinterpret_cast<const float4*>(&BL[c][dg]);
            acc[0][0] += a.x * w.x; acc[0][1] += a.x * w.y;
            acc[0][2] += a.x * w.z; acc[0][3] += a.x * w.w;
            acc[1][0] += a.y * w.x; acc[1][1] += a.y * w.y;
            acc[1][2] += a.y * w.z; acc[1][3] += a.y * w.w;
        }
    }
    if (d0 + dg < NDT) {
        float4 bv = *reinterpret_cast<const float4*>(&b1[d0 + dg]);
#pragma unroll
        for (int p = 0; p < 2; ++p) {
            int pix = pix0 + pxg + p;
            float4 v = make_float4(acc[p][0] + bv.x, acc[p][1] + bv.y,
                                   acc[p][2] + bv.z, acc[p][3] + bv.w);
            *reinterpret_cast<float4*>(&y8[(size_t)(b * 64 + pix) * NDT + d0 + dg]) = v;
        }
    }
}

// ---------------------------------------------------------------------------
// Kernel 3: per (B, head): clustering (hard + soft), cosine attention,
// out8[B][h*24+c][n].  grid 64 blocks (B*4+h), 256 threads (4 waves).
// ---------------------------------------------------------------------------
__global__ void __launch_bounds__(256) k_cluster(const float* __restrict__ y8,
                                                 const float* __restrict__ salpha,
                                                 const float* __restrict__ sbeta,
                                                 float* __restrict__ out8) {
    __shared__ float sl[5][64][25];     // [stream][pix][c] pitch 25 (bank spread)
    __shared__ float y2s[5][4][24];     // 2x2-pooled cluster centers per stream
    __shared__ float wb[2][64][5];      // assignment weights [module][token][m]
    __shared__ float aggL[8][25];       // agg sums; col 24 = count
    __shared__ float anL[8][24];        // normalized agg
    __shared__ float normL[8];

    const int bp = blockIdx.x;          // 0..63
    const int Bi = bp >> 2, h = bp & 3;
    const int tid = threadIdx.x;
    const int lane = tid & 63, wid = tid >> 6;

    for (int idx = tid; idx < 5 * 64 * 24; idx += 256) {
        int c = idx % 24;
        int pix = (idx / 24) & 63;
        int s = idx / (24 * 64);
        sl[s][pix][c] = y8[(size_t)(Bi * 64 + pix) * NDT + s * NDIM + h * NHD + c];
    }
    __syncthreads();
    for (int idx = tid; idx < 5 * 4 * 24; idx += 256) {
        int c = idx % 24;
        int m = (idx / 24) & 3;
        int s = idx / 96;
        int my = m >> 1, mx = m & 1;
        float acc = 0.f;
        for (int ry = 0; ry < 4; ++ry)
            for (int rx = 0; rx < 4; ++rx)
                acc += sl[s][(my * 4 + ry) * 8 + mx * 4 + rx][c];
        y2s[s][m][c] = acc * (1.f / 16.f);
    }
    __syncthreads();
    if (wid < 2) {
        const int i = wid, ks = 1 + 2 * i;
        float ka[24];
        float sumk2 = 0.f;
#pragma unroll
        for (int c = 0; c < 24; ++c) { ka[c] = sl[ks][lane][c]; sumk2 += ka[c] * ka[c]; }
        float sim[4];
#pragma unroll
        for (int m = 0; m < 4; ++m) {
            float kc2 = 0.f, dt = 0.f;
#pragma unroll
            for (int c = 0; c < 24; ++c) {
                float kv = y2s[ks][m][c];
                kc2 += kv * kv; dt += kv * ka[c];
            }
            sim[m] = 2.f * dt - kc2 - sumk2;    // = -d2
        }
        float w[4];
        if (i == 0) {
            int am = 0; float bv = sim[0];
#pragma unroll
            for (int m = 1; m < 4; ++m) if (sim[m] > bv) { bv = sim[m]; am = m; }
#pragma unroll
            for (int m = 0; m < 4; ++m) w[m] = (m == am) ? 1.f : 0.f;
        } else {
            float mx = fmaxf(fmaxf(sim[0], sim[1]), fmaxf(sim[2], sim[3]));
            float sum = 0.f;
#pragma unroll
            for (int m = 0; m < 4; ++m) { w[m] = expf(sim[m] - mx); sum += w[m]; }
            float inv = 1.f / sum;
#pragma unroll
            for (int m = 0; m < 4; ++m) w[m] *= inv;
        }
#pragma unroll
        for (int m = 0; m < 4; ++m) wb[i][lane][m] = w[m];
    }
    __syncthreads();
    if (tid < 200) {
        int i = tid / 100, rem = tid % 100;
        int m = rem / 25, c = rem % 25;
        int vs = 2 + 2 * i;
        float s = 0.f;
        for (int n = 0; n < 64; ++n) {
            float wv = wb[i][n][m];
            s += (c < 24) ? wv * sl[vs][n][c] : wv;
        }
        aggL[i * 4 + m][c] = s;
    }
    __syncthreads();
    if (tid < 192) {
        int mm = tid / 24, c = tid % 24;
        int i = mm >> 2, m = mm & 3;
        aggL[mm][c] = (y2s[2 + 2 * i][m][c] + aggL[mm][c]) / (1.f + aggL[mm][24]);
    }
    __syncthreads();
    if (tid < 8) {
        float s = 0.f;
        for (int c = 0; c < 24; ++c) s += aggL[tid][c] * aggL[tid][c];
        normL[tid] = sqrtf(s) + 1e-6f;
    }
    __syncthreads();
    if (tid < 192) {
        int mm = tid / 24, c = tid % 24;
        anL[mm][c] = aggL[mm][c] / normL[mm];
    }
    __syncthreads();
    {
        const int n = lane;
        float pa[24]; float p2 = 0.f;
#pragma unroll
        for (int c = 0; c < 24; ++c) { pa[c] = sl[0][n][c]; p2 += pa[c] * pa[c]; }
        float pinv = 1.f / (sqrtf(p2) + 1e-6f);
        float s2[8];
#pragma unroll
        for (int mm = 0; mm < 8; ++mm) {
            float dt = 0.f;
#pragma unroll
            for (int c = 0; c < 24; ++c) dt += anL[mm][c] * pa[c];
            s2[mm] = salpha[mm] * (dt * pinv) + sbeta[mm];
        }
        float mx = s2[0];
#pragma unroll
        for (int mm = 1; mm < 8; ++mm) mx = fmaxf(mx, s2[mm]);
        float sum = 0.f;
#pragma unroll
        for (int mm = 0; mm < 8; ++mm) { s2[mm] = expf(s2[mm] - mx); sum += s2[mm]; }
        float inv = 1.f / sum;
        const int c0 = wid * 6;
#pragma unroll
        for (int cc = 0; cc < 6; ++cc) {
            int c = c0 + cc;
            float v = 0.f;
#pragma unroll
            for (int mm = 0; mm < 8; ++mm) v += aggL[mm][c] * (s2[mm] * inv);
            out8[(size_t)(Bi * NDIM + h * NHD + c) * 64 + n] = v;
        }
    }
}

// ---------------------------------------------------------------------------
// Kernel 4 (fused proj2 + bilinear upsample + bias):
//   z[o][n] = sum_d out8[B][d][n] * W2[d][o]  (K=96, 16 o per block)
//   out[B][o][y][x] = bilerp(z[o], half-pixel, clamped) + b2[o]
// grid (24 o-tiles of 16, 16 B), 256 threads.
// Store pattern: 16 consecutive lanes write one contiguous 256B row-chunk.
// ---------------------------------------------------------------------------
__global__ void __launch_bounds__(256) k_proj2up(const float* __restrict__ out8,
                                                 const float* __restrict__ W2,
                                                 const float* __restrict__ b2,
                                                 float* __restrict__ out) {
    __shared__ float AL[96][64];   // [d][n]   24 KB
    __shared__ float WL[96][16];   // [d][o]    6 KB
    __shared__ float ZT[16][65];   // [o][n]  4.1 KB (pad 65)
    const int Bi = blockIdx.y;
    const int o0 = blockIdx.x * 16;
    const int tid = threadIdx.x;

#pragma unroll
    for (int i = 0; i < 6; ++i) {          // AL: 1536 float4
        int f = tid + i * 256;
        int d = f >> 4, ng = f & 15;
        *reinterpret_cast<float4*>(&AL[d][ng * 4]) =
            *reinterpret_cast<const float4*>(&out8[(size_t)(Bi * NDIM + d) * 64 + ng * 4]);
    }
#pragma unroll
    for (int i = 0; i < 6; ++i) {          // WL: 1536 floats
        int f = tid + i * 256;
        int d = f >> 4, o = f & 15;
        WL[d][o] = W2[d * NCIN + o0 + o];
    }
    __syncthreads();
    // ---- proj2: thread (og = tid>>6, n = tid&63) computes 4 o's
    {
        const int n = tid & 63, og = tid >> 6;
        float acc0 = 0.f, acc1 = 0.f, acc2 = 0.f, acc3 = 0.f;
#pragma unroll 8
        for (int d = 0; d < 96; ++d) {
            float a = AL[d][n];
            float4 w = *reinterpret_cast<const float4*>(&WL[d][og * 4]);
            acc0 += a * w.x; acc1 += a * w.y; acc2 += a * w.z; acc3 += a * w.w;
        }
        __syncthreads();
        ZT[og * 4 + 0][n] = acc0;
        ZT[og * 4 + 1][n] = acc1;
        ZT[og * 4 + 2][n] = acc2;
        ZT[og * 4 + 3][n] = acc3;
    }
    __syncthreads();
    // ---- upsample: thread (ol = tid>>4, xq = tid&15) writes rows as
    //      contiguous 256B chunks (float4 per lane, 16 lanes per row).
    const int ol = tid >> 4, xq = tid & 15;
    const float bias = b2[o0 + ol];

    // per-thread x-stencil: 3-tap weights onto zc[iy][0..2] at base ixb
    float uxb = 0.125f * (float)(xq * 4) - 0.4375f;
    float uxbc = fminf(fmaxf(uxb, 0.f), 7.f);
    const int ixb = (int)uxbc;
    float wa[4], wbx[4], wc[4];
#pragma unroll
    for (int j = 0; j < 4; ++j) {
        float ux  = 0.125f * (float)(xq * 4 + j) - 0.4375f;
        float uxc = fminf(fmaxf(ux, 0.f), 7.f);
        int ix0 = (int)uxc;
        int ix1 = ix0 + 1 > 7 ? 7 : ix0 + 1;
        float fx = uxc - (float)ix0;
        int k0 = ix0 - ixb, k1 = ix1 - ixb;
        wa[j]  = ((k0 == 0) ? (1.f - fx) : 0.f) + ((k1 == 0) ? fx : 0.f);
        wbx[j] = ((k0 == 1) ? (1.f - fx) : 0.f) + ((k1 == 1) ? fx : 0.f);
        wc[j]  = ((k1 == 2) ? fx : 0.f);
    }
    // preload the 8x3 input stencil for this (ol, xq): static-indexed regs
    float zc0[8], zc1[8], zc2[8];
    {
        const int i1 = ixb + 1 > 7 ? 7 : ixb + 1;
        const int i2 = ixb + 2 > 7 ? 7 : ixb + 2;
#pragma unroll
        for (int iy = 0; iy < 8; ++iy) {
            zc0[iy] = ZT[ol][iy * 8 + ixb];
            zc1[iy] = ZT[ol][iy * 8 + i1];
            zc2[iy] = ZT[ol][iy * 8 + i2];
        }
    }
    float* obase = out + (size_t)(Bi * NCIN + o0 + ol) * 4096 + xq * 4;
#pragma unroll
    for (int y = 0; y < 64; ++y) {          // full unroll: iy0/iy1/fy fold to consts
        const float u  = 0.125f * (float)y - 0.4375f;
        const float uc = fminf(fmaxf(u, 0.f), 7.f);
        const int iy0 = (int)uc;
        const int iy1 = iy0 + 1 > 7 ? 7 : iy0 + 1;
        const float fy = uc - (float)iy0;
        const float r0 = zc0[iy0] + fy * (zc0[iy1] - zc0[iy0]);
        const float r1 = zc1[iy0] + fy * (zc1[iy1] - zc1[iy0]);
        const float r2 = zc2[iy0] + fy * (zc2[iy1] - zc2[iy0]);
        float4 v;
        v.x = bias + wa[0] * r0 + wbx[0] * r1 + wc[0] * r2;
        v.y = bias + wa[1] * r0 + wbx[1] * r1 + wc[1] * r2;
        v.z = bias + wa[2] * r0 + wbx[2] * r1 + wc[2] * r2;
        v.w = bias + wa[3] * r0 + wbx[3] * r1 + wc[3] * r2;
        *reinterpret_cast<float4*>(obase + y * 64) = v;
    }
}

// ---------------------------------------------------------------------------
extern "C" void kernel_launch(void* const* d_in, const int* in_sizes, int n_in,
                              void* d_out, int out_size, void* d_ws, size_t ws_size,
                              hipStream_t stream) {
    const float* x  = (const float*)d_in[0];
    const float* W1 = (const float*)d_in[1];
    const float* b1 = (const float*)d_in[2];
    const float* W2 = (const float*)d_in[3];
    const float* b2 = (const float*)d_in[4];
    const float* sa = (const float*)d_in[5];
    const float* sb = (const float*)d_in[6];
    float* out = (float*)d_out;

    float* x8 = (float*)d_ws;                 // 16*384*64 = 393216 f
    float* y8 = x8 + 16 * 384 * 64;           // 1024*480  = 491520 f
    float* o8 = y8 + 1024 * 480;              // 16*96*64  =  98304 f

    k_pool<<<dim3(16 * 384 / 4), dim3(256), 0, stream>>>(x, x8);
    k_proj<<<dim3(8, 32), dim3(256), 0, stream>>>(x8, W1, b1, y8);
    k_cluster<<<dim3(64), dim3(256), 0, stream>>>(y8, sa, sb, o8);
    k_proj2up<<<dim3(24, 16), dim3(256), 0, stream>>>(o8, W2, b2, out);
}